// Round 1
// baseline (534.943 us; speedup 1.0000x reference)
//
#include <hip/hip_runtime.h>
#include <math.h>

namespace {

constexpr int Bsz = 4, C = 64, H = 128, W = 128, K5 = 5, HK = 640, WK = 640;
constexpr int BQ = 8;                 // query pixels per block (along w)
constexpr int THREADS = 512;          // 8 waves, 1 wave per query pixel
constexpr int SLABX = BQ * K5;        // 40 kv columns per block
constexpr int CPAD = 68;              // channel-dim pad: 16B-aligned float4, spread banks

__global__ __launch_bounds__(THREADS, 2)
void cag_fused(const float* __restrict__ fq, const float* __restrict__ fkv,
               const float* __restrict__ Wq, const float* __restrict__ Wk,
               const float* __restrict__ Wv, float* __restrict__ out)
{
    __shared__ float slab[K5 * SLABX * CPAD];   // [y][x][c], c innermost (pad 68)
    __shared__ float fq_lds[C * 9];             // [c][pix] pad 9
    __shared__ float out_lds[C * 9];

    const int blk = blockIdx.x;
    const int wb = blk & 15;            // W/BQ = 16
    const int h  = (blk >> 4) & 127;
    const int b  = blk >> 11;
    const int w0 = wb * BQ;

    const int t = threadIdx.x;

    // ---- stage feat_kv slab: rows [5h, 5h+5), cols [5*w0, 5*w0+40) ----
    {
        const float* base = fkv + (size_t)b * C * HK * WK;
        for (int i = t; i < C * K5 * SLABX; i += THREADS) {
            const int x = i % SLABX;
            const int y = (i / SLABX) % K5;
            const int c = i / (K5 * SLABX);
            slab[(y * SLABX + x) * CPAD + c] =
                base[((size_t)c * HK + (K5 * h + y)) * WK + (K5 * w0 + x)];
        }
    }
    // ---- stage feat_q tile [64 c][8 pix] ----
    {
        const int c = t / BQ, p = t % BQ;   // THREADS == C*BQ
        fq_lds[c * 9 + p] = fq[(((size_t)b * C + c) * H + h) * W + (w0 + p)];
    }
    __syncthreads();

    const int wid  = t >> 6;   // query pixel within block
    const int lane = t & 63;   // output channel

    // ---- q projection: q[lane] for pixel wid ----
    float qv = 0.f;
    {
        const float4* wrow = (const float4*)(Wq + lane * C);
        #pragma unroll
        for (int j = 0; j < 16; ++j) {
            float4 w4 = wrow[j];
            qv = fmaf(w4.x, fq_lds[(4 * j + 0) * 9 + wid], qv);
            qv = fmaf(w4.y, fq_lds[(4 * j + 1) * 9 + wid], qv);
            qv = fmaf(w4.z, fq_lds[(4 * j + 2) * 9 + wid], qv);
            qv = fmaf(w4.w, fq_lds[(4 * j + 3) * 9 + wid], qv);
        }
    }

    // ---- k,v projections for this pixel's 25 kv positions ----
    float kacc[25], vacc[25];
    #pragma unroll
    for (int n = 0; n < 25; ++n) { kacc[n] = 0.f; vacc[n] = 0.f; }

    const float4* wkrow = (const float4*)(Wk + lane * C);
    const float4* wvrow = (const float4*)(Wv + lane * C);
    #pragma unroll
    for (int ch = 0; ch < 4; ++ch) {          // 16-channel chunks of c_in
        float4 wk4[4], wv4[4];
        #pragma unroll
        for (int j = 0; j < 4; ++j) { wk4[j] = wkrow[ch * 4 + j]; wv4[j] = wvrow[ch * 4 + j]; }
        #pragma unroll
        for (int n = 0; n < 25; ++n) {
            const int ky = n / 5, kx = n % 5;
            const float4* f4 =
                (const float4*)&slab[(ky * SLABX + wid * K5 + kx) * CPAD + ch * 16];
            #pragma unroll
            for (int j = 0; j < 4; ++j) {
                const float4 f = f4[j];   // wave-uniform broadcast read
                kacc[n] = fmaf(wk4[j].x, f.x, kacc[n]);
                kacc[n] = fmaf(wk4[j].y, f.y, kacc[n]);
                kacc[n] = fmaf(wk4[j].z, f.z, kacc[n]);
                kacc[n] = fmaf(wk4[j].w, f.w, kacc[n]);
                vacc[n] = fmaf(wv4[j].x, f.x, vacc[n]);
                vacc[n] = fmaf(wv4[j].y, f.y, vacc[n]);
                vacc[n] = fmaf(wv4[j].z, f.z, vacc[n]);
                vacc[n] = fmaf(wv4[j].w, f.w, vacc[n]);
            }
        }
    }

    // ---- logits: cross-lane (channel) reduction, all lanes get result ----
    float e[25];
    #pragma unroll
    for (int n = 0; n < 25; ++n) {
        float p = qv * kacc[n];
        #pragma unroll
        for (int off = 32; off > 0; off >>= 1) p += __shfl_xor(p, off, 64);
        e[n] = p * 0.125f;   // / sqrt(64)
    }

    // ---- softmax over 25 (replicated across lanes) ----
    float m = e[0];
    #pragma unroll
    for (int n = 1; n < 25; ++n) m = fmaxf(m, e[n]);
    float s = 0.f;
    #pragma unroll
    for (int n = 0; n < 25; ++n) { e[n] = __expf(e[n] - m); s += e[n]; }
    const float inv = 1.f / s;

    // ---- PV + residual ----
    float pv = 0.f;
    #pragma unroll
    for (int n = 0; n < 25; ++n) pv = fmaf(e[n] * inv, vacc[n], pv);

    out_lds[lane * 9 + wid] = fq_lds[lane * 9 + wid] + pv;
    __syncthreads();

    // ---- transposed coalesced store ----
    {
        const int c = t / BQ, p = t % BQ;
        out[(((size_t)b * C + c) * H + h) * W + (w0 + p)] = out_lds[c * 9 + p];
    }
}

} // namespace

extern "C" void kernel_launch(void* const* d_in, const int* in_sizes, int n_in,
                              void* d_out, int out_size, void* d_ws, size_t ws_size,
                              hipStream_t stream) {
    (void)in_sizes; (void)n_in; (void)d_ws; (void)ws_size; (void)out_size;
    const float* fq  = (const float*)d_in[0];
    const float* fkv = (const float*)d_in[1];
    const float* Wq  = (const float*)d_in[2];
    const float* Wk  = (const float*)d_in[3];
    const float* Wv  = (const float*)d_in[4];
    float* out = (float*)d_out;
    dim3 grid(Bsz * H * (W / BQ));   // 4*128*16 = 8192 blocks
    cag_fused<<<grid, dim3(THREADS), 0, stream>>>(fq, fkv, Wq, Wk, Wv, out);
}

// Round 2
// 146.985 us; speedup vs baseline: 3.6394x; 3.6394x over previous
//
#include <hip/hip_runtime.h>

namespace {

constexpr int C = 64, H = 128, W = 128, K5 = 5, HK = 640, WK = 640;
constexpr int PIX = 16;          // query pixels per block
constexpr int XD = 80;           // kv columns per block (5*PIX)
constexpr int THREADS = 512;     // 8 waves
constexpr int XPAD = 84;         // slab x-dim pad (u32 units per icp-row)
constexpr int CP = 68;           // f32 row pad for [16][64] tiles
constexpr int LP = 33;           // logits row pad

__device__ inline unsigned int packbf2(float lo, float hi) {
    unsigned int a = __float_as_uint(lo), b = __float_as_uint(hi);
    a = (a + 0x7FFFu + ((a >> 16) & 1u)) >> 16;     // RNE f32->bf16
    b = (b + 0x7FFFu + ((b >> 16) & 1u)) & 0xFFFF0000u;
    return a | b;
}
__device__ inline float blo(unsigned int u) { return __uint_as_float(u << 16); }
__device__ inline float bhi(unsigned int u) { return __uint_as_float(u & 0xFFFF0000u); }

// Wqk[i][j] = 0.125 * sum_c Wk[c,i] * Wq[c,j]   (folds softmax scale 1/sqrt(64))
__global__ void prep_wqk(const float* __restrict__ Wq, const float* __restrict__ Wk,
                         float* __restrict__ Wqk) {
    int tid = blockIdx.x * 256 + threadIdx.x;    // 16*256 = 4096 = 64*64
    int i = tid >> 6, j = tid & 63;
    float acc = 0.f;
    #pragma unroll 8
    for (int c = 0; c < 64; ++c) acc = fmaf(Wk[c * 64 + i], Wq[c * 64 + j], acc);
    Wqk[i * 64 + j] = 0.125f * acc;
}

__global__ __launch_bounds__(THREADS, 4)
void cag_main(const float* __restrict__ fq, const float* __restrict__ fkv,
              const float* __restrict__ Wv, const float* __restrict__ Wqk,
              float* __restrict__ out) {
    __shared__ unsigned int slab[K5 * 32 * XPAD];   // [y][icp:32][x:84], 2 bf16/u32
    __shared__ float fq_lds[PIX * CP];              // [p][c]
    __shared__ float qk_lds[PIX * CP];              // [l][ic]
    __shared__ float lg[PIX * LP];                  // logits -> attn (in place)
    __shared__ float wsum[PIX * CP];                // [l][ic]

    const int t = threadIdx.x;
    const int bid = blockIdx.x;
    const int wb = bid & 7;                // W/PIX = 8
    const int h  = (bid >> 3) & 127;
    const int b  = bid >> 10;
    const int row0 = K5 * h, col0 = XD * wb, w0q = PIX * wb;

    // ---- stage kv slab: f32 -> packed bf16 pairs, layout [y][icp][x] ----
    {
        const float* kvb = fkv + (size_t)b * C * HK * WK;
        const size_t CSTR = (size_t)HK * WK;
        for (int i = t; i < 1600; i += THREADS) {      // 16 c4 * 5 y * 20 x4
            int x4 = i % 20;
            int y  = (i / 20) % 5;
            int c4 = i / 100;
            const float* g = kvb + ((size_t)(4 * c4) * HK + (row0 + y)) * WK + col0 + 4 * x4;
            float4 F0 = *(const float4*)(g);
            float4 F1 = *(const float4*)(g + CSTR);
            float4 F2 = *(const float4*)(g + 2 * CSTR);
            float4 F3 = *(const float4*)(g + 3 * CSTR);
            unsigned int* r0 = &slab[(y * 32 + 2 * c4) * XPAD + 4 * x4];
            unsigned int* r1 = r0 + XPAD;
            *(uint4*)r0 = make_uint4(packbf2(F0.x, F1.x), packbf2(F0.y, F1.y),
                                     packbf2(F0.z, F1.z), packbf2(F0.w, F1.w));
            *(uint4*)r1 = make_uint4(packbf2(F2.x, F3.x), packbf2(F2.y, F3.y),
                                     packbf2(F2.z, F3.z), packbf2(F2.w, F3.w));
        }
    }
    // ---- stage fq tile [p][c] ----
    {
        int p = t & 15, c = t >> 4;
        fq_lds[p * CP + c]      = fq[((size_t)(b * C + c) * H + h) * W + w0q + p];
        fq_lds[p * CP + c + 32] = fq[((size_t)(b * C + c + 32) * H + h) * W + w0q + p];
    }
    __syncthreads();

    // ---- qk[l][i] = sum_j Wqk[i][j] * fq[j][l] ----
    {
        int l = t & 15, i0 = t >> 4;
        const float4* wr0 = (const float4*)(Wqk + i0 * 64);
        const float4* wr1 = (const float4*)(Wqk + (i0 + 32) * 64);
        const float4* fv  = (const float4*)(fq_lds + l * CP);
        float a0 = 0.f, a1 = 0.f;
        #pragma unroll
        for (int j = 0; j < 16; ++j) {
            float4 f = fv[j], w0 = wr0[j], w1 = wr1[j];
            a0 = fmaf(w0.x, f.x, a0); a0 = fmaf(w0.y, f.y, a0);
            a0 = fmaf(w0.z, f.z, a0); a0 = fmaf(w0.w, f.w, a0);
            a1 = fmaf(w1.x, f.x, a1); a1 = fmaf(w1.y, f.y, a1);
            a1 = fmaf(w1.z, f.z, a1); a1 = fmaf(w1.w, f.w, a1);
        }
        qk_lds[l * CP + i0]      = a0;
        qk_lds[l * CP + i0 + 32] = a1;
    }
    __syncthreads();

    // ---- logits[l][n] = sum_ic qk[l][ic] * slab[ic][n,l] ----
    {
        int n = t & 31, l = t >> 5;
        if (n < 25) {
            int ky = n / 5, kx = n - 5 * ky;
            int x = 5 * l + kx;
            const unsigned int* sp = &slab[(ky * 32) * XPAD + x];
            const float4* qv = (const float4*)(qk_lds + l * CP);
            float acc = 0.f;
            #pragma unroll
            for (int q4 = 0; q4 < 8; ++q4) {           // 4 icp = 8 ic per iter
                float4 qa = qv[2 * q4], qb = qv[2 * q4 + 1];
                unsigned int s0 = sp[(4 * q4 + 0) * XPAD];
                unsigned int s1 = sp[(4 * q4 + 1) * XPAD];
                unsigned int s2 = sp[(4 * q4 + 2) * XPAD];
                unsigned int s3 = sp[(4 * q4 + 3) * XPAD];
                acc = fmaf(qa.x, blo(s0), acc); acc = fmaf(qa.y, bhi(s0), acc);
                acc = fmaf(qa.z, blo(s1), acc); acc = fmaf(qa.w, bhi(s1), acc);
                acc = fmaf(qb.x, blo(s2), acc); acc = fmaf(qb.y, bhi(s2), acc);
                acc = fmaf(qb.z, blo(s3), acc); acc = fmaf(qb.w, bhi(s3), acc);
            }
            lg[l * LP + n] = acc;
        }
    }
    __syncthreads();

    // ---- softmax over n (25), two rows per wave via 32-lane halves ----
    {
        int lane = t & 63, w = t >> 6;
        int n = lane & 31;
        int l = 2 * w + (lane >> 5);
        float v = (n < 25) ? lg[l * LP + n] : -1e30f;
        float m = v;
        #pragma unroll
        for (int off = 16; off; off >>= 1) m = fmaxf(m, __shfl_xor(m, off, 32));
        float e = __expf(v - m);
        float s = e;
        #pragma unroll
        for (int off = 16; off; off >>= 1) s += __shfl_xor(s, off, 32);
        if (n < 25) lg[l * LP + n] = e / s;
    }
    __syncthreads();

    // ---- wsum[l][ic] = sum_n attn[l][n] * slab[ic][n,l] ----
    {
        int l = t & 15, icp = t >> 4;
        float alo = 0.f, ahi = 0.f;
        #pragma unroll
        for (int n = 0; n < 25; ++n) {
            const int ky = n / 5, kx = n - 5 * ky;
            float a = lg[l * LP + n];
            unsigned int s = slab[(ky * 32 + icp) * XPAD + 5 * l + kx];
            alo = fmaf(a, blo(s), alo);
            ahi = fmaf(a, bhi(s), ahi);
        }
        wsum[l * CP + 2 * icp]     = alo;
        wsum[l * CP + 2 * icp + 1] = ahi;
    }
    __syncthreads();

    // ---- out[oc][l] = fq[oc][l] + sum_ic Wv[oc][ic] * wsum[l][ic] ----
    {
        int p = t & 15, o0 = t >> 4;
        const float4* wv0 = (const float4*)(Wv + o0 * 64);
        const float4* wv1 = (const float4*)(Wv + (o0 + 32) * 64);
        const float4* ws  = (const float4*)(wsum + p * CP);
        float a0 = 0.f, a1 = 0.f;
        #pragma unroll
        for (int j = 0; j < 16; ++j) {
            float4 f = ws[j], w0 = wv0[j], w1 = wv1[j];
            a0 = fmaf(w0.x, f.x, a0); a0 = fmaf(w0.y, f.y, a0);
            a0 = fmaf(w0.z, f.z, a0); a0 = fmaf(w0.w, f.w, a0);
            a1 = fmaf(w1.x, f.x, a1); a1 = fmaf(w1.y, f.y, a1);
            a1 = fmaf(w1.z, f.z, a1); a1 = fmaf(w1.w, f.w, a1);
        }
        size_t ob = ((size_t)(b * C + o0) * H + h) * W + w0q + p;
        out[ob]                    = fq_lds[p * CP + o0]      + a0;
        out[ob + (size_t)32 * H * W] = fq_lds[p * CP + o0 + 32] + a1;
    }
}

} // namespace

extern "C" void kernel_launch(void* const* d_in, const int* in_sizes, int n_in,
                              void* d_out, int out_size, void* d_ws, size_t ws_size,
                              hipStream_t stream) {
    (void)in_sizes; (void)n_in; (void)ws_size; (void)out_size;
    const float* fq  = (const float*)d_in[0];
    const float* fkv = (const float*)d_in[1];
    const float* Wq  = (const float*)d_in[2];
    const float* Wk  = (const float*)d_in[3];
    const float* Wv  = (const float*)d_in[4];
    float* out = (float*)d_out;
    float* Wqk = (float*)d_ws;                      // 16 KB scratch

    prep_wqk<<<dim3(16), dim3(256), 0, stream>>>(Wq, Wk, Wqk);
    cag_main<<<dim3(4 * 128 * 8), dim3(THREADS), 0, stream>>>(fq, fkv, Wv, Wqk, out);
}